// Round 5
// baseline (359.246 us; speedup 1.0000x reference)
//
#include <hip/hip_runtime.h>

typedef _Float16 f16x8 __attribute__((ext_vector_type(8)));
typedef float    f32x4 __attribute__((ext_vector_type(4)));

#define N_ROWS 8192
#define DIM 64
#define EPS 1e-8f
#define LOG2E 1.4426950408889634f
#define SHIFT 64.0f                      // exp terms scaled by 2^64
#define SHIFT_LN 44.361419555836499802f  // 64 * ln(2)
#define JCHUNK 256
#define NT (JCHUNK / 16)                 // 16 j-tiles per block

// ws: top[8192] | bot[8192] | sq[8192] (f32) | xh[8192*64] | xl[8192*64] (f16)

// fused: zero top/bot/out + f16 split + row norms. one wave per row.
__global__ void snn_prep(const float* __restrict__ x, _Float16* __restrict__ xh,
                         _Float16* __restrict__ xl, float* __restrict__ sq,
                         float* __restrict__ top, float* __restrict__ bot,
                         float* __restrict__ out) {
    const int gt = blockIdx.x * 256 + threadIdx.x;
    if (gt < N_ROWS) { top[gt] = 0.0f; bot[gt] = 0.0f; }
    if (gt == 0) out[0] = 0.0f;
    const int row = gt >> 6, lane = threadIdx.x & 63;
    float v = x[row * DIM + lane];
    _Float16 h = (_Float16)v;
    _Float16 l = (_Float16)(v - (float)h);
    xh[row * DIM + lane] = h;
    xl[row * DIM + lane] = l;
    float s = v * v;
    #pragma unroll
    for (int off = 32; off > 0; off >>= 1) s += __shfl_xor(s, off, 64);
    if (lane == 0) sq[row] = s;
}

// block = 4 waves, each wave owns 64 i-rows; block j-chunk = 256, nt loop x16
__global__ __launch_bounds__(256, 3) void snn_mfma(
    const _Float16* __restrict__ xh, const _Float16* __restrict__ xl,
    const float* __restrict__ sq, const int* __restrict__ y,
    const float* __restrict__ w,
    float* __restrict__ top, float* __restrict__ bot)
{
    __shared__ float s_sq[JCHUNK];
    __shared__ int   s_y[JCHUNK];
    const int tid = threadIdx.x, wv = tid >> 6, lane = tid & 63;
    const int mrow = lane & 15, kq = lane >> 4;
    const int I0 = blockIdx.x * 256 + wv * 64;
    const int j0 = blockIdx.y * JCHUNK;
    s_sq[tid] = sq[j0 + tid];
    s_y[tid]  = y[j0 + tid];
    __syncthreads();

    // A fragments resident for the whole block lifetime (64 VGPRs)
    f16x8 ah[4][2], al[4][2];
    #pragma unroll
    for (int mt = 0; mt < 4; mt++)
        #pragma unroll
        for (int kc = 0; kc < 2; kc++) {
            int a = (I0 + mt * 16 + mrow) * DIM + kc * 32 + kq * 8;
            ah[mt][kc] = *(const f16x8*)(xh + a);
            al[mt][kc] = *(const f16x8*)(xl + a);
        }

    // per-slot row metadata: i = I0 + mt*16 + kq*4 + r ; labels packed 4/VGPR
    float sqi[4][4]; int ypack[4];
    #pragma unroll
    for (int mt = 0; mt < 4; mt++) {
        int yp = 0;
        #pragma unroll
        for (int r = 0; r < 4; r++) {
            int i = I0 + mt * 16 + kq * 4 + r;
            sqi[mt][r] = sq[i];
            yp |= (y[i] & 255) << (8 * r);
        }
        ypack[mt] = yp;
    }

    float ts[4][4], bs[4][4];
    #pragma unroll
    for (int mt = 0; mt < 4; mt++)
        #pragma unroll
        for (int r = 0; r < 4; r++) { ts[mt][r] = 0.0f; bs[mt][r] = 0.0f; }

    const float c1 = -w[0] * LOG2E;

    for (int nt = 0; nt < NT; nt++) {
        const int jb = j0 + nt * 16;
        const int bbase = (jb + mrow) * DIM + kq * 8;
        f16x8 bh0 = *(const f16x8*)(xh + bbase);
        f16x8 bh1 = *(const f16x8*)(xh + bbase + 32);
        f16x8 bl0 = *(const f16x8*)(xl + bbase);
        f16x8 bl1 = *(const f16x8*)(xl + bbase + 32);
        const float sqj = s_sq[nt * 16 + mrow];
        const int   yj  = s_y[nt * 16 + mrow];
        const int   j   = jb + mrow;

        f32x4 acc[4];
        #pragma unroll
        for (int mt = 0; mt < 4; mt++) acc[mt] = (f32x4){0.f, 0.f, 0.f, 0.f};
        #pragma unroll
        for (int mt = 0; mt < 4; mt++)
            acc[mt] = __builtin_amdgcn_mfma_f32_16x16x32_f16(ah[mt][0], bh0, acc[mt], 0, 0, 0);
        #pragma unroll
        for (int mt = 0; mt < 4; mt++)
            acc[mt] = __builtin_amdgcn_mfma_f32_16x16x32_f16(ah[mt][1], bh1, acc[mt], 0, 0, 0);
        #pragma unroll
        for (int mt = 0; mt < 4; mt++)
            acc[mt] = __builtin_amdgcn_mfma_f32_16x16x32_f16(ah[mt][0], bl0, acc[mt], 0, 0, 0);
        #pragma unroll
        for (int mt = 0; mt < 4; mt++)
            acc[mt] = __builtin_amdgcn_mfma_f32_16x16x32_f16(ah[mt][1], bl1, acc[mt], 0, 0, 0);
        #pragma unroll
        for (int mt = 0; mt < 4; mt++)
            acc[mt] = __builtin_amdgcn_mfma_f32_16x16x32_f16(al[mt][0], bh0, acc[mt], 0, 0, 0);
        #pragma unroll
        for (int mt = 0; mt < 4; mt++)
            acc[mt] = __builtin_amdgcn_mfma_f32_16x16x32_f16(al[mt][1], bh1, acc[mt], 0, 0, 0);

        // fused epilogue: d2 -> dist -> exp -> masked accumulation
        #pragma unroll
        for (int mt = 0; mt < 4; mt++)
            #pragma unroll
            for (int r = 0; r < 4; r++) {
                int i = I0 + mt * 16 + kq * 4 + r;
                float d2 = fmaf(-2.0f, acc[mt][r], sqi[mt][r] + sqj);
                d2 = fmaxf(d2, 0.0f);
                float dist = __builtin_amdgcn_sqrtf(d2);
                float e2 = exp2f(fmaf(c1, dist, SHIFT));
                bool offd = (i != j);
                bool same = offd && (yj == ((ypack[mt] >> (8 * r)) & 255));
                bs[mt][r] += offd ? e2 : 0.0f;
                ts[mt][r] += same ? e2 : 0.0f;
            }
    }

    // reduce across the 16 lanes (mrow) sharing each row, then one atomic/row
    #pragma unroll
    for (int mt = 0; mt < 4; mt++)
        #pragma unroll
        for (int r = 0; r < 4; r++) {
            float tv = ts[mt][r], bv = bs[mt][r];
            #pragma unroll
            for (int off = 1; off < 16; off <<= 1) {
                tv += __shfl_xor(tv, off, 64);
                bv += __shfl_xor(bv, off, 64);
            }
            if (mrow == 0) {
                int i = I0 + mt * 16 + kq * 4 + r;
                atomicAdd(&top[i], tv);
                atomicAdd(&bot[i], bv);
            }
        }
}

__global__ __launch_bounds__(256) void snn_final(
    const float* __restrict__ top, const float* __restrict__ bot,
    float* __restrict__ out)
{
    const int i = blockIdx.x * 256 + threadIdx.x;
    float t = top[i];                    // top * 2^64, normal fp32
    float b = bot[i] * 0x1p-64f + EPS;   // bot tiny; +eps dominates
    float acc = (logf(t) - SHIFT_LN) - logf(b);
    #pragma unroll
    for (int off = 32; off > 0; off >>= 1) acc += __shfl_xor(acc, off, 64);
    __shared__ float red[4];
    if ((threadIdx.x & 63) == 0) red[threadIdx.x >> 6] = acc;
    __syncthreads();
    if (threadIdx.x == 0) {
        float s = red[0] + red[1] + red[2] + red[3];
        atomicAdd(out, -s / (float)N_ROWS);
    }
}

extern "C" void kernel_launch(void* const* d_in, const int* in_sizes, int n_in,
                              void* d_out, int out_size, void* d_ws, size_t ws_size,
                              hipStream_t stream) {
    const float* x = (const float*)d_in[0];
    const int*   y = (const int*)d_in[1];
    const float* w = (const float*)d_in[2];
    float* out = (float*)d_out;

    float* ws  = (float*)d_ws;
    float* top = ws;
    float* bot = ws + N_ROWS;
    float* sq  = ws + 2 * N_ROWS;
    _Float16* xh = (_Float16*)(ws + 3 * N_ROWS);
    _Float16* xl = xh + (size_t)N_ROWS * DIM;

    snn_prep<<<N_ROWS / 4, 256, 0, stream>>>(x, xh, xl, sq, top, bot, out);
    snn_mfma<<<dim3(N_ROWS / 256, N_ROWS / JCHUNK), 256, 0, stream>>>(xh, xl, sq, y, w, top, bot);
    snn_final<<<N_ROWS / 256, 256, 0, stream>>>(top, bot, out);
}

// Round 6
// 123.307 us; speedup vs baseline: 2.9134x; 2.9134x over previous
//
#include <hip/hip_runtime.h>

typedef _Float16 f16x8 __attribute__((ext_vector_type(8)));
typedef float    f32x4 __attribute__((ext_vector_type(4)));

#define N_ROWS 8192
#define DIM 64
#define EPS 1e-8f
#define LOG2E 1.4426950408889634f
#define SHIFT 64.0f                      // exp terms scaled by 2^64
#define SHIFT_LN 44.361419555836499802f  // 64 * ln(2)
#define JCHUNK 256
#define NT (JCHUNK / 16)                 // 16 j-tiles per block

// ws: top[8192] | bot[8192] | sq[8192] (f32) | xh[8192*64] | xl[8192*64] (f16)

// fused: zero top/bot/out + f16 split + row norms. one wave per row.
__global__ void snn_prep(const float* __restrict__ x, _Float16* __restrict__ xh,
                         _Float16* __restrict__ xl, float* __restrict__ sq,
                         float* __restrict__ top, float* __restrict__ bot,
                         float* __restrict__ out) {
    const int gt = blockIdx.x * 256 + threadIdx.x;
    if (gt < N_ROWS) { top[gt] = 0.0f; bot[gt] = 0.0f; }
    if (gt == 0) out[0] = 0.0f;
    const int row = gt >> 6, lane = threadIdx.x & 63;
    float v = x[row * DIM + lane];
    _Float16 h = (_Float16)v;
    _Float16 l = (_Float16)(v - (float)h);
    xh[row * DIM + lane] = h;
    xl[row * DIM + lane] = l;
    float s = v * v;
    #pragma unroll
    for (int off = 32; off > 0; off >>= 1) s += __shfl_xor(s, off, 64);
    if (lane == 0) sq[row] = s;
}

// block = 4 waves, each wave owns 64 i-rows; block j-chunk = 256, nt loop x16
// launch_bounds(256,2): VGPR cap 256 — R4's proven no-spill regime.
// (256,3) capped at ~84 VGPR and spilled the A-frags -> 324 MB scratch writes (R5).
__global__ __launch_bounds__(256, 2) void snn_mfma(
    const _Float16* __restrict__ xh, const _Float16* __restrict__ xl,
    const float* __restrict__ sq, const int* __restrict__ y,
    const float* __restrict__ w,
    float* __restrict__ top, float* __restrict__ bot)
{
    __shared__ float s_sq[JCHUNK];
    __shared__ int   s_y[JCHUNK];
    const int tid = threadIdx.x, wv = tid >> 6, lane = tid & 63;
    const int mrow = lane & 15, kq = lane >> 4;
    const int I0 = blockIdx.x * 256 + wv * 64;
    const int j0 = blockIdx.y * JCHUNK;
    s_sq[tid] = sq[j0 + tid];
    s_y[tid]  = y[j0 + tid];
    __syncthreads();

    // A fragments resident for the whole block lifetime (64 VGPRs)
    f16x8 ah[4][2], al[4][2];
    #pragma unroll
    for (int mt = 0; mt < 4; mt++)
        #pragma unroll
        for (int kc = 0; kc < 2; kc++) {
            int a = (I0 + mt * 16 + mrow) * DIM + kc * 32 + kq * 8;
            ah[mt][kc] = *(const f16x8*)(xh + a);
            al[mt][kc] = *(const f16x8*)(xl + a);
        }

    // per-slot row metadata: i = I0 + mt*16 + kq*4 + r ; labels packed 4/VGPR
    float sqi[4][4]; int ypack[4];
    #pragma unroll
    for (int mt = 0; mt < 4; mt++) {
        int yp = 0;
        #pragma unroll
        for (int r = 0; r < 4; r++) {
            int i = I0 + mt * 16 + kq * 4 + r;
            sqi[mt][r] = sq[i];
            yp |= (y[i] & 255) << (8 * r);
        }
        ypack[mt] = yp;
    }

    float ts[4][4], bs[4][4];
    #pragma unroll
    for (int mt = 0; mt < 4; mt++)
        #pragma unroll
        for (int r = 0; r < 4; r++) { ts[mt][r] = 0.0f; bs[mt][r] = 0.0f; }

    const float c1 = -w[0] * LOG2E;

    for (int nt = 0; nt < NT; nt++) {
        const int jb = j0 + nt * 16;
        const int bbase = (jb + mrow) * DIM + kq * 8;
        f16x8 bh0 = *(const f16x8*)(xh + bbase);
        f16x8 bh1 = *(const f16x8*)(xh + bbase + 32);
        f16x8 bl0 = *(const f16x8*)(xl + bbase);
        f16x8 bl1 = *(const f16x8*)(xl + bbase + 32);
        const float sqj = s_sq[nt * 16 + mrow];
        const int   yj  = s_y[nt * 16 + mrow];
        const int   j   = jb + mrow;

        f32x4 acc[4];
        #pragma unroll
        for (int mt = 0; mt < 4; mt++) acc[mt] = (f32x4){0.f, 0.f, 0.f, 0.f};
        #pragma unroll
        for (int mt = 0; mt < 4; mt++)
            acc[mt] = __builtin_amdgcn_mfma_f32_16x16x32_f16(ah[mt][0], bh0, acc[mt], 0, 0, 0);
        #pragma unroll
        for (int mt = 0; mt < 4; mt++)
            acc[mt] = __builtin_amdgcn_mfma_f32_16x16x32_f16(ah[mt][1], bh1, acc[mt], 0, 0, 0);
        #pragma unroll
        for (int mt = 0; mt < 4; mt++)
            acc[mt] = __builtin_amdgcn_mfma_f32_16x16x32_f16(ah[mt][0], bl0, acc[mt], 0, 0, 0);
        #pragma unroll
        for (int mt = 0; mt < 4; mt++)
            acc[mt] = __builtin_amdgcn_mfma_f32_16x16x32_f16(ah[mt][1], bl1, acc[mt], 0, 0, 0);
        #pragma unroll
        for (int mt = 0; mt < 4; mt++)
            acc[mt] = __builtin_amdgcn_mfma_f32_16x16x32_f16(al[mt][0], bh0, acc[mt], 0, 0, 0);
        #pragma unroll
        for (int mt = 0; mt < 4; mt++)
            acc[mt] = __builtin_amdgcn_mfma_f32_16x16x32_f16(al[mt][1], bh1, acc[mt], 0, 0, 0);

        // fused epilogue: d2 -> dist -> exp -> masked accumulation
        #pragma unroll
        for (int mt = 0; mt < 4; mt++)
            #pragma unroll
            for (int r = 0; r < 4; r++) {
                int i = I0 + mt * 16 + kq * 4 + r;
                float d2 = fmaf(-2.0f, acc[mt][r], sqi[mt][r] + sqj);
                d2 = fmaxf(d2, 0.0f);
                float dist = __builtin_amdgcn_sqrtf(d2);
                float e2 = exp2f(fmaf(c1, dist, SHIFT));
                bool offd = (i != j);
                bool same = offd && (yj == ((ypack[mt] >> (8 * r)) & 255));
                bs[mt][r] += offd ? e2 : 0.0f;
                ts[mt][r] += same ? e2 : 0.0f;
            }
    }

    // reduce across the 16 lanes (mrow) sharing each row, then one atomic/row
    #pragma unroll
    for (int mt = 0; mt < 4; mt++)
        #pragma unroll
        for (int r = 0; r < 4; r++) {
            float tv = ts[mt][r], bv = bs[mt][r];
            #pragma unroll
            for (int off = 1; off < 16; off <<= 1) {
                tv += __shfl_xor(tv, off, 64);
                bv += __shfl_xor(bv, off, 64);
            }
            if (mrow == 0) {
                int i = I0 + mt * 16 + kq * 4 + r;
                atomicAdd(&top[i], tv);
                atomicAdd(&bot[i], bv);
            }
        }
}

__global__ __launch_bounds__(256) void snn_final(
    const float* __restrict__ top, const float* __restrict__ bot,
    float* __restrict__ out)
{
    const int i = blockIdx.x * 256 + threadIdx.x;
    float t = top[i];                    // top * 2^64, normal fp32
    float b = bot[i] * 0x1p-64f + EPS;   // bot tiny; +eps dominates
    float acc = (logf(t) - SHIFT_LN) - logf(b);
    #pragma unroll
    for (int off = 32; off > 0; off >>= 1) acc += __shfl_xor(acc, off, 64);
    __shared__ float red[4];
    if ((threadIdx.x & 63) == 0) red[threadIdx.x >> 6] = acc;
    __syncthreads();
    if (threadIdx.x == 0) {
        float s = red[0] + red[1] + red[2] + red[3];
        atomicAdd(out, -s / (float)N_ROWS);
    }
}

extern "C" void kernel_launch(void* const* d_in, const int* in_sizes, int n_in,
                              void* d_out, int out_size, void* d_ws, size_t ws_size,
                              hipStream_t stream) {
    const float* x = (const float*)d_in[0];
    const int*   y = (const int*)d_in[1];
    const float* w = (const float*)d_in[2];
    float* out = (float*)d_out;

    float* ws  = (float*)d_ws;
    float* top = ws;
    float* bot = ws + N_ROWS;
    float* sq  = ws + 2 * N_ROWS;
    _Float16* xh = (_Float16*)(ws + 3 * N_ROWS);
    _Float16* xl = xh + (size_t)N_ROWS * DIM;

    snn_prep<<<N_ROWS / 4, 256, 0, stream>>>(x, xh, xl, sq, top, bot, out);
    snn_mfma<<<dim3(N_ROWS / 256, N_ROWS / JCHUNK), 256, 0, stream>>>(xh, xl, sq, y, w, top, bot);
    snn_final<<<N_ROWS / 256, 256, 0, stream>>>(top, bot, out);
}